// Round 5
// baseline (168.129 us; speedup 1.0000x reference)
//
#include <hip/hip_runtime.h>

// ThreePhaseTerm: sparse chemistry RHS assembly on MI355X.
//
// Round-5 structure (thread = batch; kill LDS pipe + conflicts entirely):
//   Round 4's gather kernel was ~50% LDS-pipe-bound (random ys/w gathers,
//   8.1M conflict cycles). Since all 256 batches consume the IDENTICAL edge
//   stream, we flip the mapping: threadIdx.x = batch, edge runs walked
//   serially. Edge records become wave-uniform scalar loads; y-gathers become
//   coalesced 256B vector loads from transposed tables yT[s][b], wT[s][b]
//   (w = y*den; rows 800/801/802 = 1 / k_s2m / k_m2s). No LDS, no atomics in
//   the hot loop; direct stores cover d_out fully (no memset needed).
//
//   Pipeline: memset(cnt,part) -> hist -> scan -> reorder(1,2) -> transpose
//             -> pack gl streams -> gainloss -> ksm -> final.

constexpr int B_    = 256;
constexpr int S_    = 800;
constexpr int E1_   = 60000;
constexpr int E2_   = 180000;
constexpr int ET_   = E1_ + E2_;      // 240000 combined final edges
constexpr int E1G_  = 15000;
constexpr int E2G_  = 45000;
constexpr int E1L_  = 15000;
constexpr int E2L_  = 45000;
constexpr int NSMT_ = 600;
constexpr float LOG2E_ = 1.4426950408889634f;
constexpr float EPS_   = 1e-30f;
constexpr int PAD  = 16;              // int stride for sort counters
constexpr int GCH  = 500;             // gainloss blocks (15000/500=30, 45000/500=90)
// unified second-operand rows in wT
constexpr int IB_ONE = 800, IB_KS = 801, IB_KM = 802, WROWS = 804;

#if defined(__has_builtin)
#if __has_builtin(__builtin_amdgcn_exp2f)
#define FAST_EXP2(x) __builtin_amdgcn_exp2f(x)
#endif
#endif
#ifndef FAST_EXP2
#define FAST_EXP2(x) exp2f(x)
#endif

// ---------------------------------------------------------------------------
// Sort phase A: histogram of product indices (padded counters, pre-zeroed).
// ---------------------------------------------------------------------------
__global__ __launch_bounds__(256) void hist_kernel(
    const int* __restrict__ p1, const int* __restrict__ p2,
    int* __restrict__ cnt)
{
    int e = blockIdx.x * 256 + threadIdx.x;
    if (e < E1_)      atomicAdd(&cnt[p1[e] * PAD], 1);
    else if (e < ET_) atomicAdd(&cnt[p2[e - E1_] * PAD], 1);
}

// ---------------------------------------------------------------------------
// Sort phase B: exclusive scan of 800 bins (one block), init rank counters.
// ---------------------------------------------------------------------------
__global__ __launch_bounds__(1024) void scan_kernel(
    const int* __restrict__ cnt, int* __restrict__ starts,
    int* __restrict__ rank)
{
    __shared__ int sc[1024];
    int t = threadIdx.x;
    sc[t] = (t < S_) ? cnt[t * PAD] : 0;
    __syncthreads();
    for (int off = 1; off < 1024; off <<= 1) {
        int v = (t >= off) ? sc[t - off] : 0;
        __syncthreads();
        sc[t] += v;
        __syncthreads();
    }
    if (t < S_) {
        int ex = t ? sc[t - 1] : 0;
        starts[t] = ex;
        rank[t * PAD] = ex;
    }
    if (t == S_ - 1) starts[S_] = sc[t];
}

// ---------------------------------------------------------------------------
// Sort phase C: reorder+pack 1st-order final edges into sorted stream.
// bits = ia | ib<<10 ; ib in {800 (plain), 801 (k_s2m), 802 (k_m2s)}.
// ---------------------------------------------------------------------------
__global__ __launch_bounds__(256) void reorder1_kernel(
    const float* __restrict__ alpha, const float* __restrict__ beta,
    const float* __restrict__ gam,
    const int* __restrict__ k, const int* __restrict__ r,
    const int* __restrict__ p, const int* __restrict__ s,
    int* __restrict__ rank, float4* __restrict__ sorted)
{
    int e = blockIdx.x * 256 + threadIdx.x;
    if (e >= E1_) return;
    int kk = k[e], rr = r[e], pp = p[e], ss = s[e];
    float a = alpha[kk], b = beta[kk], g = gam[kk];
    int ib = IB_ONE;
    if (kk < 2 * NSMT_) {
        ib = (kk < NSMT_) ? IB_KS : IB_KM;
        a = 1.0f; b = 0.0f; g = 0.0f;    // exp2(0)=1; override coeff via wT row
    }
    float a_s = ss ? a : -a;
    int bits = rr | (ib << 10);
    int slot = atomicAdd(&rank[pp * PAD], 1);
    sorted[slot] = make_float4(a_s, b, g, __int_as_float(bits));
}

// ---------------------------------------------------------------------------
// Sort phase C': reorder+pack 2nd-order final edges. bits = ra | rb<<10.
// ---------------------------------------------------------------------------
__global__ __launch_bounds__(256) void reorder2_kernel(
    const float* __restrict__ alpha, const float* __restrict__ beta,
    const float* __restrict__ gam,
    const int* __restrict__ k, const int* __restrict__ ra,
    const int* __restrict__ rb, const int* __restrict__ p,
    const int* __restrict__ s,
    int* __restrict__ rank, float4* __restrict__ sorted)
{
    int e = blockIdx.x * 256 + threadIdx.x;
    if (e >= E2_) return;
    int kk = k[e], ia = ra[e], ib = rb[e], pp = p[e], ss = s[e];
    float a = alpha[kk], b = beta[kk], g = gam[kk];
    float a_s = ss ? a : -a;
    int bits = ia | (ib << 10);
    int slot = atomicAdd(&rank[pp * PAD], 1);
    sorted[slot] = make_float4(a_s, b, g, __int_as_float(bits));
}

// ---------------------------------------------------------------------------
// Transpose: yT[s][b] = y[b][s]; wT[s][b] = y[b][s]*den[b]; wT[800][b] = 1.
// Grid 200 blocks = (25 s-tiles) x (8 b-tiles), 256 threads, 32x32 LDS tile.
// ---------------------------------------------------------------------------
__global__ __launch_bounds__(256) void transpose_kernel(
    const float* __restrict__ y, const float* __restrict__ den_gas,
    float* __restrict__ yT, float* __restrict__ wT)
{
    __shared__ float tile[32][33];
    const int sb = blockIdx.x % 25, bb = blockIdx.x / 25;
    const int tx = threadIdx.x & 31, ty = threadIdx.x >> 5;   // ty in [0,8)
    const int s0 = sb * 32, b0 = bb * 32;

    #pragma unroll
    for (int j = 0; j < 4; ++j) {
        int bl = ty + 8 * j;                       // b_local
        tile[bl][tx] = y[(b0 + bl) * S_ + s0 + tx];  // coalesced along s
    }
    __syncthreads();
    const float d = den_gas[b0 + tx];
    #pragma unroll
    for (int j = 0; j < 4; ++j) {
        int sl = ty + 8 * j;                       // s_local
        float v = tile[tx][sl];
        yT[(s0 + sl) * B_ + b0 + tx] = v;          // coalesced along b
        wT[(s0 + sl) * B_ + b0 + tx] = v * d;
    }
    if (blockIdx.x == 0) wT[IB_ONE * B_ + threadIdx.x] = 1.0f;
}

// ---------------------------------------------------------------------------
// Pack gain/loss streams (reduction-only; p-window folded into sign/zero).
// ---------------------------------------------------------------------------
__global__ __launch_bounds__(256) void pack1gl_kernel(
    int E,
    const float* __restrict__ alpha, const float* __restrict__ beta,
    const float* __restrict__ gam,
    const int* __restrict__ k, const int* __restrict__ r,
    const int* __restrict__ p, const int* __restrict__ s,
    float4* __restrict__ out)
{
    int e = blockIdx.x * 256 + threadIdx.x;
    if (e >= E) return;
    int kk = k[e], rr = r[e], pp = p[e], ss = s[e];
    float a = alpha[kk], b = beta[kk], g = gam[kk];
    if (!(pp >= 200 && pp < 500)) a = 0.0f;
    float a_s = ss ? a : -a;
    int bits = rr | (IB_ONE << 10);
    out[e] = make_float4(a_s, b, g, __int_as_float(bits));
}

__global__ __launch_bounds__(256) void pack2gl_kernel(
    int E,
    const float* __restrict__ alpha, const float* __restrict__ beta,
    const float* __restrict__ gam,
    const int* __restrict__ k, const int* __restrict__ ra,
    const int* __restrict__ rb, const int* __restrict__ p,
    const int* __restrict__ s,
    float4* __restrict__ out)
{
    int e = blockIdx.x * 256 + threadIdx.x;
    if (e >= E) return;
    int kk = k[e], ia = ra[e], ib = rb[e], pp = p[e], ss = s[e];
    float a = alpha[kk], b = beta[kk], g = gam[kk];
    if (!(pp >= 200 && pp < 500)) a = 0.0f;
    float a_s = ss ? a : -a;
    int bits = ia | (ib << 10);
    out[e] = make_float4(a_s, b, g, __int_as_float(bits));
}

// ---------------------------------------------------------------------------
// unified edge term: a_s * exp2(beta*lt2 + gamma*nivt) * yT[ia][b] * wT[ib][b]
// Edge record q is wave-uniform (scalar loads); yT/wT loads are coalesced.
// ---------------------------------------------------------------------------
__device__ __forceinline__ float edge_term(
    float4 q, int t, const float* __restrict__ yT, const float* __restrict__ wT,
    float lt2, float nivt)
{
    int bits = __float_as_int(q.w);
    int ia = bits & 1023, ib = (bits >> 10) & 1023;
    return q.x * FAST_EXP2(fmaf(q.y, lt2, q.z * nivt))
         * yT[ia * B_ + t] * wT[ib * B_ + t];
}

// ---------------------------------------------------------------------------
// K1: gain/loss sums.  grid = GCH blocks; thread = batch; register accum.
// ---------------------------------------------------------------------------
__global__ __launch_bounds__(256) void gainloss_kernel(
    const float* __restrict__ T_gas,
    const float* __restrict__ yT, const float* __restrict__ wT,
    const float4* __restrict__ g1, const float4* __restrict__ g2,
    const float4* __restrict__ l1, const float4* __restrict__ l2,
    float* __restrict__ part)            // [2*B] {gain, loss}, pre-zeroed
{
    const int t = threadIdx.x, c = blockIdx.x;
    const float T = T_gas[t];
    const float lt2  = log2f(T * (1.0f / 300.0f));
    const float nivt = -LOG2E_ / T;

    float gain = 0.f, loss = 0.f;
    {
        const int n = E1G_ / GCH;  const float4* s = g1 + c * n;
        #pragma unroll 5
        for (int i = 0; i < n; ++i) gain += edge_term(s[i], t, yT, wT, lt2, nivt);
    }
    {
        const int n = E2G_ / GCH;  const float4* s = g2 + c * n;
        #pragma unroll 5
        for (int i = 0; i < n; ++i) gain += edge_term(s[i], t, yT, wT, lt2, nivt);
    }
    {
        const int n = E1L_ / GCH;  const float4* s = l1 + c * n;
        #pragma unroll 5
        for (int i = 0; i < n; ++i) loss += edge_term(s[i], t, yT, wT, lt2, nivt);
    }
    {
        const int n = E2L_ / GCH;  const float4* s = l2 + c * n;
        #pragma unroll 5
        for (int i = 0; i < n; ++i) loss += edge_term(s[i], t, yT, wT, lt2, nivt);
    }
    atomicAdd(&part[2 * t + 0], gain);
    atomicAdd(&part[2 * t + 1], loss);
}

// ---------------------------------------------------------------------------
// ksm: per-batch k_s2m/k_m2s -> wT rows 801/802.  grid = B_ blocks, 64 thr.
// ---------------------------------------------------------------------------
__global__ __launch_bounds__(64) void ksm_kernel(
    const float* __restrict__ y, const float* __restrict__ part,
    float* __restrict__ wT)
{
    const int b = blockIdx.x, lane = threadIdx.x;
    float vs = 0.f, vm = 0.f;
    #pragma unroll
    for (int j = 0; j < 5; ++j) {
        int i = lane + 64 * j;
        if (i < 300) { vs += y[b * S_ + 200 + i]; vm += y[b * S_ + 500 + i]; }
    }
    #pragma unroll
    for (int o = 32; o > 0; o >>= 1) {
        vs += __shfl_down(vs, o, 64);
        vm += __shfl_down(vm, o, 64);
    }
    if (lane == 0) {
        float gain = part[2 * b + 0], loss = part[2 * b + 1];
        float nl = 1e-2f * (vs + vm);
        float decay = fminf(2.0f / fmaxf(nl, EPS_), 1.0f);
        wT[IB_KS * B_ + b] = gain / fmaxf(vs, EPS_);
        wT[IB_KM * B_ + b] = loss / fmaxf(vm, EPS_) * decay;
    }
}

// ---------------------------------------------------------------------------
// K2: final RHS.  grid = S_ blocks (one product each); thread = batch.
// Serial walk of the product's sorted edge run; 4x unrolled; direct store.
// ---------------------------------------------------------------------------
__global__ __launch_bounds__(256) void final_kernel(
    const float* __restrict__ T_gas,
    const float* __restrict__ yT, const float* __restrict__ wT,
    const float4* __restrict__ sorted, const int* __restrict__ starts,
    float* __restrict__ out)
{
    const int t = threadIdx.x, p = blockIdx.x;
    const float T = T_gas[t];
    const float lt2  = log2f(T * (1.0f / 300.0f));
    const float nivt = -LOG2E_ / T;

    const int s0 = starts[p], s1 = starts[p + 1];
    float acc = 0.f;
    int e = s0;
    for (; e + 4 <= s1; e += 4) {
        float4 q0 = sorted[e],     q1 = sorted[e + 1];
        float4 q2 = sorted[e + 2], q3 = sorted[e + 3];
        float t0 = edge_term(q0, t, yT, wT, lt2, nivt);
        float t1 = edge_term(q1, t, yT, wT, lt2, nivt);
        float t2 = edge_term(q2, t, yT, wT, lt2, nivt);
        float t3 = edge_term(q3, t, yT, wT, lt2, nivt);
        acc += (t0 + t1) + (t2 + t3);
    }
    for (; e < s1; ++e) acc += edge_term(sorted[e], t, yT, wT, lt2, nivt);

    out[t * S_ + p] = acc;    // covers every (b,p) exactly once
}

// ---------------------------------------------------------------------------
extern "C" void kernel_launch(void* const* d_in, const int* in_sizes, int n_in,
                              void* d_out, int out_size, void* d_ws, size_t ws_size,
                              hipStream_t stream) {
    const float* y       = (const float*)d_in[1];
    const float* den_gas = (const float*)d_in[2];
    const float* T_gas   = (const float*)d_in[3];
    const float* alpha   = (const float*)d_in[4];
    const float* beta    = (const float*)d_in[5];
    const float* gam     = (const float*)d_in[6];
    const int* k1  = (const int*)d_in[7];
    const int* r1  = (const int*)d_in[8];
    const int* p1  = (const int*)d_in[9];
    const int* s1  = (const int*)d_in[10];
    const int* k2  = (const int*)d_in[11];
    const int* ra2 = (const int*)d_in[12];
    const int* rb2 = (const int*)d_in[13];
    const int* p2  = (const int*)d_in[14];
    const int* s2  = (const int*)d_in[15];
    const int* k1g  = (const int*)d_in[16];
    const int* r1g  = (const int*)d_in[17];
    const int* p1g  = (const int*)d_in[18];
    const int* s1g  = (const int*)d_in[19];
    const int* k2g  = (const int*)d_in[20];
    const int* ra2g = (const int*)d_in[21];
    const int* rb2g = (const int*)d_in[22];
    const int* p2g  = (const int*)d_in[23];
    const int* s2g  = (const int*)d_in[24];
    const int* k1l  = (const int*)d_in[25];
    const int* r1l  = (const int*)d_in[26];
    const int* p1l  = (const int*)d_in[27];
    const int* s1l  = (const int*)d_in[28];
    const int* k2l  = (const int*)d_in[29];
    const int* ra2l = (const int*)d_in[30];
    const int* rb2l = (const int*)d_in[31];
    const int* p2l  = (const int*)d_in[32];
    const int* s2l  = (const int*)d_in[33];

    // workspace layout (~7.5 MB)
    char* wsp = (char*)d_ws;
    size_t off = 0;
    float4* sorted = (float4*)(wsp + off); off += (size_t)ET_  * 16;
    float4* g1 = (float4*)(wsp + off); off += (size_t)E1G_ * 16;
    float4* g2 = (float4*)(wsp + off); off += (size_t)E2G_ * 16;
    float4* l1 = (float4*)(wsp + off); off += (size_t)E1L_ * 16;
    float4* l2 = (float4*)(wsp + off); off += (size_t)E2L_ * 16;
    float* yT  = (float*)(wsp + off); off += (size_t)S_ * B_ * 4;
    float* wT  = (float*)(wsp + off); off += (size_t)WROWS * B_ * 4;
    int* cnt    = (int*)(wsp + off); off += (size_t)S_ * PAD * 4;
    int* rank   = (int*)(wsp + off); off += (size_t)S_ * PAD * 4;
    int* starts = (int*)(wsp + off); off += (size_t)(S_ + 1) * 4;
    float* part = (float*)(wsp + off); off += (size_t)2 * B_ * 4;

    float* out = (float*)d_out;

    hipMemsetAsync(cnt,  0, (size_t)S_ * PAD * 4, stream);
    hipMemsetAsync(part, 0, (size_t)2 * B_ * sizeof(float), stream);

    // counting sort of final edges by product p (batch-independent)
    hist_kernel<<<(ET_ + 255) / 256, 256, 0, stream>>>(p1, p2, cnt);
    scan_kernel<<<1, 1024, 0, stream>>>(cnt, starts, rank);
    reorder1_kernel<<<(E1_ + 255) / 256, 256, 0, stream>>>(
        alpha, beta, gam, k1, r1, p1, s1, rank, sorted);
    reorder2_kernel<<<(E2_ + 255) / 256, 256, 0, stream>>>(
        alpha, beta, gam, k2, ra2, rb2, p2, s2, rank, sorted);

    // transposed y / w tables
    transpose_kernel<<<200, 256, 0, stream>>>(y, den_gas, yT, wT);

    // gain/loss packed streams
    pack1gl_kernel<<<(E1G_ + 255) / 256, 256, 0, stream>>>(E1G_, alpha, beta, gam, k1g, r1g, p1g, s1g, g1);
    pack2gl_kernel<<<(E2G_ + 255) / 256, 256, 0, stream>>>(E2G_, alpha, beta, gam, k2g, ra2g, rb2g, p2g, s2g, g2);
    pack1gl_kernel<<<(E1L_ + 255) / 256, 256, 0, stream>>>(E1L_, alpha, beta, gam, k1l, r1l, p1l, s1l, l1);
    pack2gl_kernel<<<(E2L_ + 255) / 256, 256, 0, stream>>>(E2L_, alpha, beta, gam, k2l, ra2l, rb2l, p2l, s2l, l2);

    // gain/loss scalars
    gainloss_kernel<<<GCH, 256, 0, stream>>>(T_gas, yT, wT, g1, g2, l1, l2, part);
    ksm_kernel<<<B_, 64, 0, stream>>>(y, part, wT);

    // final assembly (no atomics, no LDS; fully covers d_out)
    final_kernel<<<S_, 256, 0, stream>>>(T_gas, yT, wT, sorted, starts, out);
}